// Round 2
// baseline (82.256 us; speedup 1.0000x reference)
//
#include <hip/hip_runtime.h>
#include <hip/hip_bf16.h>

// FDLT: out[b,m,l] = sum_k psiHat[b,m,k] * Em[m][k][l]   (all fp32)
//   Em[m][k][l] = Cm[m] * sum_n XF_sel(m)[k][n] * Dm[l][n]
// B=64, M=2B-1=127, 2B=128, BATCH=512. Output fp32 [512,127,64].
// XF_sel: m odd -> XFc, m even -> XFs  (since (B-1)%2==1 -> cInd = odd rows).

#define B_     64
#define M_     127
#define TWOB_  128
#define NB_    512

// ---------------------------------------------------------------------------
// Kernel 1: build Em[m][k][l] into workspace (127*128*64 floats = 4.16 MB).
// One block per m. COO rows are sorted by (m,l,n); row range found by bsearch.
// ---------------------------------------------------------------------------
__global__ __launch_bounds__(256) void build_Em(
    const float* __restrict__ Cm,
    const float* __restrict__ XFc,
    const float* __restrict__ XFs,
    const float* __restrict__ Dval,
    const int*   __restrict__ Drow,
    const int*   __restrict__ Dcol,
    int nnz,
    float* __restrict__ Em)
{
    __shared__ float Dm[B_ * B_];   // dense [l][n], 16 KB
    const int m = blockIdx.x;
    const int t = threadIdx.x;

    for (int i = t; i < B_ * B_; i += 256) Dm[i] = 0.f;

    // row range [m*64, (m+1)*64) in sorted COO (redundant per-thread bsearch)
    int lo, hi;
    {
        int target = m * B_;
        int a = 0, b = nnz;
        while (a < b) { int mid = (a + b) >> 1; if (Drow[mid] < target) a = mid + 1; else b = mid; }
        lo = a;
        target = (m + 1) * B_;
        b = nnz;
        while (a < b) { int mid = (a + b) >> 1; if (Drow[mid] < target) a = mid + 1; else b = mid; }
        hi = a;
    }
    __syncthreads();
    for (int i = lo + t; i < hi; i += 256) {
        int l = Drow[i] - m * B_;
        int n = Dcol[i] - m * TWOB_;
        Dm[l * B_ + n] = Dval[i];
    }
    __syncthreads();

    const float* __restrict__ XF = (m & 1) ? XFc : XFs;
    const float cm = Cm[m];
    const int k  = t & 127;          // each lane owns one k-row of XF
    const int l0 = (t >> 7) * 32;    // two halves of l-range across 256 thr
    const float4* __restrict__ XFrow = reinterpret_cast<const float4*>(XF + k * TWOB_);

    for (int l = l0; l < l0 + 32; ++l) {
        // n in [0, l]; Dm is zero beyond, so round quads up
        const int nq = (l >> 2) + 1;
        const float4* __restrict__ dmrow = reinterpret_cast<const float4*>(Dm + l * B_);
        float acc = 0.f;
        for (int q = 0; q < nq; ++q) {
            float4 xf = XFrow[q];   // L1-resident across n
            float4 dm = dmrow[q];   // LDS broadcast (uniform l across wave)
            acc += xf.x * dm.x + xf.y * dm.y + xf.z * dm.z + xf.w * dm.w;
        }
        Em[(m * TWOB_ + k) * B_ + l] = cm * acc;
    }
}

// ---------------------------------------------------------------------------
// Kernel 2: out[b0+bb, m, l] = sum_k A[bb][k] * Em[m][k][l]
// Grid: (8 batch-tiles of 64) x (127 m). 256 threads = 16(tl) x 16(tb).
// LDS: As[64][128] XOR-swizzled (16B-unit swizzle, row&7) + Es[128][64].
// Thread computes 4(b) x 4(l) fp32 micro-tile; inner loop over k-quads:
// 2x ds_read_b128 per (i), 16 FMA per k.
// ---------------------------------------------------------------------------
__global__ __launch_bounds__(256) void fdlt_gemm(
    const float* __restrict__ psiHat,
    const float* __restrict__ Em,
    float* __restrict__ out)
{
    __shared__ float As[64 * 128];  // 32 KB, swizzled: word = bb*128 + ((c4^(bb&7))<<2)+j
    __shared__ float Es[128 * 64];  // 32 KB, linear [k][l]

    const int m  = blockIdx.y;
    const int b0 = blockIdx.x * 64;
    const int t  = threadIdx.x;

    // stage A tile: psiHat[b0+bb][m][0..127], coalesced float4, swizzled LDS dst
    #pragma unroll
    for (int j = 0; j < 8; ++j) {
        int i  = t + j * 256;        // 0..2047 float4s
        int bb = i >> 5;
        int c4 = i & 31;
        float4 v = *reinterpret_cast<const float4*>(
            psiHat + ((size_t)(b0 + bb) * M_ + m) * TWOB_ + (c4 << 2));
        *reinterpret_cast<float4*>(As + bb * 128 + ((c4 ^ (bb & 7)) << 2)) = v;
    }
    // stage Em tile (8192 floats, linear copy)
    {
        const float4* __restrict__ esrc = reinterpret_cast<const float4*>(Em + (size_t)m * (TWOB_ * B_));
        float4* __restrict__ edst = reinterpret_cast<float4*>(Es);
        #pragma unroll
        for (int j = 0; j < 8; ++j) edst[t + j * 256] = esrc[t + j * 256];
    }
    __syncthreads();

    const int tl = t & 15;           // l-tile: cols tl*4..tl*4+3
    const int tb = t >> 4;           // b-tile: rows tb*4..tb*4+3

    float acc[4][4] = {};
    int rbase[4], rx[4];
    #pragma unroll
    for (int i = 0; i < 4; ++i) {
        int r = tb * 4 + i;
        rbase[i] = r * 128;
        rx[i]    = r & 7;
    }

    #pragma unroll 4
    for (int kk = 0; kk < 32; ++kk) {        // k = 4*kk .. 4*kk+3
        float4 e0 = *reinterpret_cast<const float4*>(Es + (kk * 4 + 0) * 64 + tl * 4);
        float4 e1 = *reinterpret_cast<const float4*>(Es + (kk * 4 + 1) * 64 + tl * 4);
        float4 e2 = *reinterpret_cast<const float4*>(Es + (kk * 4 + 2) * 64 + tl * 4);
        float4 e3 = *reinterpret_cast<const float4*>(Es + (kk * 4 + 3) * 64 + tl * 4);
        #pragma unroll
        for (int i = 0; i < 4; ++i) {
            float4 a = *reinterpret_cast<const float4*>(As + rbase[i] + ((kk ^ rx[i]) << 2));
            acc[i][0] += a.x * e0.x + a.y * e1.x + a.z * e2.x + a.w * e3.x;
            acc[i][1] += a.x * e0.y + a.y * e1.y + a.z * e2.y + a.w * e3.y;
            acc[i][2] += a.x * e0.z + a.y * e1.z + a.z * e2.z + a.w * e3.z;
            acc[i][3] += a.x * e0.w + a.y * e1.w + a.z * e2.w + a.w * e3.w;
        }
    }

    // epilogue: fp32 float4 stores (16B, contiguous across tl)
    #pragma unroll
    for (int i = 0; i < 4; ++i) {
        int b = b0 + tb * 4 + i;
        float4 v;
        v.x = acc[i][0]; v.y = acc[i][1]; v.z = acc[i][2]; v.w = acc[i][3];
        *reinterpret_cast<float4*>(out + ((size_t)b * M_ + m) * B_ + tl * 4) = v;
    }
}

extern "C" void kernel_launch(void* const* d_in, const int* in_sizes, int n_in,
                              void* d_out, int out_size, void* d_ws, size_t ws_size,
                              hipStream_t stream) {
    const float* psiHat = (const float*)d_in[0];
    const float* Cm     = (const float*)d_in[1];
    const float* XFc    = (const float*)d_in[2];
    const float* XFs    = (const float*)d_in[3];
    const float* Dval   = (const float*)d_in[4];
    const int*   Drow   = (const int*)d_in[5];
    const int*   Dcol   = (const int*)d_in[6];
    const int nnz = in_sizes[4];

    float* Em = (float*)d_ws;   // needs 127*128*64*4 = 4,161,536 bytes

    build_Em<<<dim3(M_), dim3(256), 0, stream>>>(Cm, XFc, XFs, Dval, Drow, Dcol, nnz, Em);
    fdlt_gemm<<<dim3(8, M_), dim3(256), 0, stream>>>(psiHat, Em, (float*)d_out);
}

// Round 3
// 40.719 us; speedup vs baseline: 2.0201x; 2.0201x over previous
//
#include <hip/hip_runtime.h>
#include <hip/hip_bf16.h>

// FDLT: out[b,m,l] = sum_k psiHat[b,m,k] * Em[m][k][l]   (all fp32)
//   Em[m][k][l] = Cm[m] * sum_n XF_sel(m)[k][n] * Dm[l][n]
// B=64, M=2B-1=127, 2B=128, BATCH=512. Output fp32 [512,127,64].
// XF_sel: m odd -> XFc, m even -> XFs  (since (B-1)%2==1 -> cInd = odd rows).

#define B_     64
#define M_     127
#define TWOB_  128
#define NB_    512

// ---------------------------------------------------------------------------
// Kernel 1: build Em[m][k][l] into workspace (127*128*64 floats = 4.16 MB).
// Grid 4 x 127: block = (l-quarter of 16, m). 256 thr = 128 k x 2 l-halves.
// Each thread: 8 independent accumulators (8 l's), inner loop over n-quads:
// 1 global XF load (L1-hit) + 8 LDS broadcast reads + 32 FMA -> ILP 8.
// Round-2 fix: old version was 1 block/m, serial acc chain -> 58 us at
// 4% occupancy / 3% VALUBusy (latency-bound). This one: 508 blocks + ILP.
// ---------------------------------------------------------------------------
__global__ __launch_bounds__(256) void build_Em(
    const float* __restrict__ Cm,
    const float* __restrict__ XFc,
    const float* __restrict__ XFs,
    const float* __restrict__ Dval,
    const int*   __restrict__ Drow,
    const int*   __restrict__ Dcol,
    int nnz,
    float* __restrict__ Em)
{
    __shared__ float Dm[16 * B_];   // dense [l-l0][n], 4 KB
    const int m  = blockIdx.y;
    const int l0 = blockIdx.x * 16;
    const int t  = threadIdx.x;

    for (int i = t; i < 16 * B_; i += 256) Dm[i] = 0.f;

    // COO rows sorted; row id = m*64 + l. Segment for l in [l0, l0+16).
    int lo, hi;
    {
        int target = m * B_ + l0;
        int a = 0, b = nnz;
        while (a < b) { int mid = (a + b) >> 1; if (Drow[mid] < target) a = mid + 1; else b = mid; }
        lo = a;
        target = m * B_ + l0 + 16;
        b = nnz;
        while (a < b) { int mid = (a + b) >> 1; if (Drow[mid] < target) a = mid + 1; else b = mid; }
        hi = a;
    }
    __syncthreads();
    for (int i = lo + t; i < hi; i += 256) {
        int l = Drow[i] - m * B_ - l0;
        int n = Dcol[i] - m * TWOB_;
        Dm[l * B_ + n] = Dval[i];
    }
    __syncthreads();

    const float* __restrict__ XF = (m & 1) ? XFc : XFs;
    const float cm = Cm[m];
    const int k  = t & 127;          // lane's k-row of XF
    const int lh = t >> 7;           // 0/1: which 8 of the 16 l's
    const float4* __restrict__ XFrow = reinterpret_cast<const float4*>(XF + k * TWOB_);
    const float4* __restrict__ dmq   = reinterpret_cast<const float4*>(Dm) + lh * 8 * 16;

    const int nq = ((l0 + 15) >> 2) + 1;   // n <= max l in this chunk
    float acc[8] = {};
    for (int q = 0; q < nq; ++q) {
        float4 xf = XFrow[q];              // L1-resident (XF = 64 KB)
        #pragma unroll
        for (int j = 0; j < 8; ++j) {
            float4 dm = dmq[j * 16 + q];   // broadcast across the 128 k-lanes
            acc[j] += xf.x * dm.x + xf.y * dm.y + xf.z * dm.z + xf.w * dm.w;
        }
    }
    float* __restrict__ dst = Em + (size_t)(m * TWOB_ + k) * B_ + l0 + lh * 8;
    #pragma unroll
    for (int j = 0; j < 8; ++j) dst[j] = cm * acc[j];
}

// ---------------------------------------------------------------------------
// Kernel 2: out[b0+bb, m, l] = sum_k A[bb][k] * Em[m][k][l]
// Grid: (8 batch-tiles of 64) x (127 m). 256 threads = 16(tl) x 16(tb).
// LDS: As[64][128] XOR-swizzled (16B-unit swizzle, row&7) + Es[128][64].
// Thread computes 4(b) x 4(l) fp32 micro-tile; inner loop over k-quads:
// 2x ds_read_b128 per (i), 16 FMA per k.   (unchanged from round 2)
// ---------------------------------------------------------------------------
__global__ __launch_bounds__(256) void fdlt_gemm(
    const float* __restrict__ psiHat,
    const float* __restrict__ Em,
    float* __restrict__ out)
{
    __shared__ float As[64 * 128];  // 32 KB, swizzled: word = bb*128 + ((c4^(bb&7))<<2)+j
    __shared__ float Es[128 * 64];  // 32 KB, linear [k][l]

    const int m  = blockIdx.y;
    const int b0 = blockIdx.x * 64;
    const int t  = threadIdx.x;

    // stage A tile: psiHat[b0+bb][m][0..127], coalesced float4, swizzled LDS dst
    #pragma unroll
    for (int j = 0; j < 8; ++j) {
        int i  = t + j * 256;        // 0..2047 float4s
        int bb = i >> 5;
        int c4 = i & 31;
        float4 v = *reinterpret_cast<const float4*>(
            psiHat + ((size_t)(b0 + bb) * M_ + m) * TWOB_ + (c4 << 2));
        *reinterpret_cast<float4*>(As + bb * 128 + ((c4 ^ (bb & 7)) << 2)) = v;
    }
    // stage Em tile (8192 floats, linear copy)
    {
        const float4* __restrict__ esrc = reinterpret_cast<const float4*>(Em + (size_t)m * (TWOB_ * B_));
        float4* __restrict__ edst = reinterpret_cast<float4*>(Es);
        #pragma unroll
        for (int j = 0; j < 8; ++j) edst[t + j * 256] = esrc[t + j * 256];
    }
    __syncthreads();

    const int tl = t & 15;           // l-tile: cols tl*4..tl*4+3
    const int tb = t >> 4;           // b-tile: rows tb*4..tb*4+3

    float acc[4][4] = {};
    int rbase[4], rx[4];
    #pragma unroll
    for (int i = 0; i < 4; ++i) {
        int r = tb * 4 + i;
        rbase[i] = r * 128;
        rx[i]    = r & 7;
    }

    #pragma unroll 4
    for (int kk = 0; kk < 32; ++kk) {        // k = 4*kk .. 4*kk+3
        float4 e0 = *reinterpret_cast<const float4*>(Es + (kk * 4 + 0) * 64 + tl * 4);
        float4 e1 = *reinterpret_cast<const float4*>(Es + (kk * 4 + 1) * 64 + tl * 4);
        float4 e2 = *reinterpret_cast<const float4*>(Es + (kk * 4 + 2) * 64 + tl * 4);
        float4 e3 = *reinterpret_cast<const float4*>(Es + (kk * 4 + 3) * 64 + tl * 4);
        #pragma unroll
        for (int i = 0; i < 4; ++i) {
            float4 a = *reinterpret_cast<const float4*>(As + rbase[i] + ((kk ^ rx[i]) << 2));
            acc[i][0] += a.x * e0.x + a.y * e1.x + a.z * e2.x + a.w * e3.x;
            acc[i][1] += a.x * e0.y + a.y * e1.y + a.z * e2.y + a.w * e3.y;
            acc[i][2] += a.x * e0.z + a.y * e1.z + a.z * e2.z + a.w * e3.z;
            acc[i][3] += a.x * e0.w + a.y * e1.w + a.z * e2.w + a.w * e3.w;
        }
    }

    // epilogue: fp32 float4 stores (16B, contiguous across tl)
    #pragma unroll
    for (int i = 0; i < 4; ++i) {
        int b = b0 + tb * 4 + i;
        float4 v;
        v.x = acc[i][0]; v.y = acc[i][1]; v.z = acc[i][2]; v.w = acc[i][3];
        *reinterpret_cast<float4*>(out + ((size_t)b * M_ + m) * B_ + tl * 4) = v;
    }
}

extern "C" void kernel_launch(void* const* d_in, const int* in_sizes, int n_in,
                              void* d_out, int out_size, void* d_ws, size_t ws_size,
                              hipStream_t stream) {
    const float* psiHat = (const float*)d_in[0];
    const float* Cm     = (const float*)d_in[1];
    const float* XFc    = (const float*)d_in[2];
    const float* XFs    = (const float*)d_in[3];
    const float* Dval   = (const float*)d_in[4];
    const int*   Drow   = (const int*)d_in[5];
    const int*   Dcol   = (const int*)d_in[6];
    const int nnz = in_sizes[4];

    float* Em = (float*)d_ws;   // needs 127*128*64*4 = 4,161,536 bytes

    build_Em<<<dim3(4, M_), dim3(256), 0, stream>>>(Cm, XFc, XFs, Dval, Drow, Dcol, nnz, Em);
    fdlt_gemm<<<dim3(8, M_), dim3(256), 0, stream>>>(psiHat, Em, (float*)d_out);
}

// Round 4
// 29.472 us; speedup vs baseline: 2.7910x; 1.3816x over previous
//
#include <hip/hip_runtime.h>
#include <hip/hip_bf16.h>

// FDLT: out[b,m,l] = sum_k psiHat[b,m,k] * Em[m][k][l]   (fp32 in/out)
//   Em[m][k][l] = Cm[m] * sum_n XF_sel(m)[k][n] * Dm[l][n],  n only 0..63
// B=64, M=127, 2B=128, BATCH=512. Round 4: Em stored bf16 [m][l][k];
// GEMM via mfma_f32_16x16x32_bf16 (psiHat converted to bf16 while staging).

#define B_     64
#define M_     127
#define TWOB_  128

using bf16x8 = __attribute__((ext_vector_type(8))) short;  // 8 bf16 (4 VGPR)
using f32x4  = __attribute__((ext_vector_type(4))) float;

__device__ inline short f2bf(float x) {
    __hip_bfloat16 h = __float2bfloat16(x);
    return *reinterpret_cast<short*>(&h);
}

// ---------------------------------------------------------------------------
// Kernel 1: Em_bf16[m][l][k] = bf16( Cm[m] * sum_n XF[k][n]*Dm[l][n] ).
// Grid (4,127): block = 16 l's of one m. 256 thr = 128 k x 2 l-halves.
// n-extent uniform (16 quads, Dm zero-padded) -> XF row preloaded into 16
// float4 REGISTERS with full unroll (kills round-3's serial L2-latency chain;
// XF is 64KB > 32KB L1). Dm reads are wave-uniform LDS broadcasts (free).
// ---------------------------------------------------------------------------
__global__ __launch_bounds__(256) void build_Em(
    const float* __restrict__ Cm,
    const float* __restrict__ XFc,
    const float* __restrict__ XFs,
    const float* __restrict__ Dval,
    const int*   __restrict__ Drow,
    const int*   __restrict__ Dcol,
    int nnz,
    __hip_bfloat16* __restrict__ Em)
{
    __shared__ float Dm[16 * B_];   // [l-l0][n], 4 KB, zero-padded
    const int m  = blockIdx.y;
    const int l0 = blockIdx.x * 16;
    const int t  = threadIdx.x;

    for (int i = t; i < 16 * B_; i += 256) Dm[i] = 0.f;

    // COO rows sorted; row id = m*64 + l. Segment for l in [l0, l0+16).
    int lo, hi;
    {
        int target = m * B_ + l0;
        int a = 0, b = nnz;
        while (a < b) { int mid = (a + b) >> 1; if (Drow[mid] < target) a = mid + 1; else b = mid; }
        lo = a;
        target = m * B_ + l0 + 16;
        b = nnz;
        while (a < b) { int mid = (a + b) >> 1; if (Drow[mid] < target) a = mid + 1; else b = mid; }
        hi = a;
    }
    __syncthreads();
    for (int i = lo + t; i < hi; i += 256) {
        int l = Drow[i] - m * B_ - l0;
        int n = Dcol[i] - m * TWOB_;
        Dm[l * B_ + n] = Dval[i];
    }
    __syncthreads();

    const float* __restrict__ XF = (m & 1) ? XFc : XFs;
    const float cm = Cm[m];
    const int k  = t & 127;          // lane's k-row of XF
    const int lh = t >> 7;           // 0/1: which 8 of the 16 l's

    const float4* __restrict__ XFrow = reinterpret_cast<const float4*>(XF + k * TWOB_);
    float4 xf[16];
    #pragma unroll
    for (int q = 0; q < 16; ++q) xf[q] = XFrow[q];   // 16 independent loads

    const float4* __restrict__ dmq = reinterpret_cast<const float4*>(Dm) + (lh * 8) * 16;
    float acc[8] = {};
    #pragma unroll
    for (int q = 0; q < 16; ++q) {
        #pragma unroll
        for (int j = 0; j < 8; ++j) {
            float4 dm = dmq[j * 16 + q];   // wave-uniform broadcast
            acc[j] += xf[q].x * dm.x + xf[q].y * dm.y + xf[q].z * dm.z + xf[q].w * dm.w;
        }
    }
    #pragma unroll
    for (int j = 0; j < 8; ++j) {
        int l = l0 + lh * 8 + j;
        Em[(size_t)(m * B_ + l) * TWOB_ + k] = __float2bfloat16(cm * acc[j]);
    }
}

// ---------------------------------------------------------------------------
// Kernel 2: per m, out[64b x 64l] += A[64b x 128k] @ E[128k x 64l] via MFMA.
// Grid (8 batch-tiles, 127 m), 256 thr = 4 waves; wave w owns b-rows w*16..+15
// and all 64 l (4 C-tiles of 16x16). K = 4 steps of 32.
// LDS: As[64][128] bf16, Es(l-major)[64][128] bf16, both XOR-swizzled in 16B
// units (u ^= row&15) so fragment ds_read_b128 (16 lanes, row-stride 256B)
// spreads across all banks. A/B frag: lane holds row/col = lane&15,
// k = ks*32 + (lane>>4)*8 + i  ->  16B unit g = ks*4 + (lane>>4).
// C/D: col = lane&15, row = (lane>>4)*4 + reg   [m89-verified layout].
// ---------------------------------------------------------------------------
__global__ __launch_bounds__(256) void fdlt_gemm(
    const float* __restrict__ psiHat,
    const __hip_bfloat16* __restrict__ Em,
    float* __restrict__ out)
{
    __shared__ short As[64 * 128];   // 16 KB bf16 bits
    __shared__ short Es[64 * 128];   // 16 KB, [l][k]

    const int m  = blockIdx.y;
    const int b0 = blockIdx.x * 64;
    const int t  = threadIdx.x;

    // stage A: psiHat fp32 [64 rows x 128 k] -> bf16, swizzled
    #pragma unroll
    for (int j = 0; j < 8; ++j) {
        int i   = t + j * 256;       // 0..2047 float4s
        int row = i >> 5;
        int c4  = i & 31;            // float4 index within row
        float4 v = *reinterpret_cast<const float4*>(
            psiHat + ((size_t)(b0 + row) * M_ + m) * TWOB_ + (c4 << 2));
        short4 s;
        s.x = f2bf(v.x); s.y = f2bf(v.y); s.z = f2bf(v.z); s.w = f2bf(v.w);
        int u  = c4 >> 1;            // 16B unit, two float4 -> one unit
        int hf = c4 & 1;
        *reinterpret_cast<short4*>(As + row * 128 + ((u ^ (row & 15)) << 3) + (hf << 2)) = s;
    }
    // stage Es: Em[m] is already bf16 [l][k] -> linear 16KB copy, swizzled
    {
        const uint4* __restrict__ esrc = reinterpret_cast<const uint4*>(Em + (size_t)m * (B_ * TWOB_));
        #pragma unroll
        for (int j = 0; j < 4; ++j) {
            int lin = t + j * 256;   // 0..1023 16B units
            int row = lin >> 4;      // l
            int u   = lin & 15;
            uint4 v = esrc[lin];
            *reinterpret_cast<uint4*>(Es + row * 128 + ((u ^ (row & 15)) << 3)) = v;
        }
    }
    __syncthreads();

    const int w    = t >> 6;         // wave id: b-rows w*16..w*16+15
    const int lane = t & 63;
    const int lr   = lane & 15;
    const int lg   = lane >> 4;      // k-group

    f32x4 acc[4];
    #pragma unroll
    for (int nt = 0; nt < 4; ++nt) acc[nt] = (f32x4){0.f, 0.f, 0.f, 0.f};

    const int arow = w * 16 + lr;
    const short* __restrict__ abase = As + arow * 128;

    #pragma unroll
    for (int ks = 0; ks < 4; ++ks) {
        int g = ks * 4 + lg;
        bf16x8 af = *reinterpret_cast<const bf16x8*>(abase + ((g ^ lr) << 3));
        #pragma unroll
        for (int nt = 0; nt < 4; ++nt) {
            int er = nt * 16 + lr;
            bf16x8 bf = *reinterpret_cast<const bf16x8*>(Es + er * 128 + ((g ^ lr) << 3));
            acc[nt] = __builtin_amdgcn_mfma_f32_16x16x32_bf16(af, bf, acc[nt], 0, 0, 0);
        }
    }

    // epilogue: C col = lane&15 (= l within tile), row = lg*4 + r (= b within 16)
    #pragma unroll
    for (int nt = 0; nt < 4; ++nt) {
        #pragma unroll
        for (int r = 0; r < 4; ++r) {
            int b = b0 + w * 16 + lg * 4 + r;
            int l = nt * 16 + lr;
            out[((size_t)b * M_ + m) * B_ + l] = acc[nt][r];
        }
    }
}

extern "C" void kernel_launch(void* const* d_in, const int* in_sizes, int n_in,
                              void* d_out, int out_size, void* d_ws, size_t ws_size,
                              hipStream_t stream) {
    const float* psiHat = (const float*)d_in[0];
    const float* Cm     = (const float*)d_in[1];
    const float* XFc    = (const float*)d_in[2];
    const float* XFs    = (const float*)d_in[3];
    const float* Dval   = (const float*)d_in[4];
    const int*   Drow   = (const int*)d_in[5];
    const int*   Dcol   = (const int*)d_in[6];
    const int nnz = in_sizes[4];

    __hip_bfloat16* Em = (__hip_bfloat16*)d_ws;   // 127*64*128*2 = 2,080,768 B

    build_Em<<<dim3(4, M_), dim3(256), 0, stream>>>(Cm, XFc, XFs, Dval, Drow, Dcol, nnz, Em);
    fdlt_gemm<<<dim3(8, M_), dim3(256), 0, stream>>>(psiHat, Em, (float*)d_out);
}

// Round 5
// 29.311 us; speedup vs baseline: 2.8064x; 1.0055x over previous
//
#include <hip/hip_runtime.h>
#include <hip/hip_bf16.h>

// FDLT: out[b,m,l] = sum_k psiHat[b,m,k] * Em[m][k][l]   (fp32 in/out)
//   Em[m][k][l] = Cm[m] * sum_n XF_sel(m)[k][n] * Dm[l][n],  n only 0..63
// B=64, M=127, 2B=128, BATCH=512. Em stored bf16 [m][l][k].
// Round 5: fdlt_gemm restaged via global_load_lds DMA (fp32 A tile, swizzled
// SOURCE + linear LDS dest), swapped MFMA operands -> float4 epilogue,
// XCD-aware m mapping. build_Em UNchanged from round 4 (attribution).

#define B_     64
#define M_     127
#define TWOB_  128

using bf16x8 = __attribute__((ext_vector_type(8))) short;  // 8 bf16 (4 VGPR)
using f32x4  = __attribute__((ext_vector_type(4))) float;

__device__ inline short f2bf(float x) {
    __hip_bfloat16 h = __float2bfloat16(x);
    return *reinterpret_cast<short*>(&h);
}

// ---------------------------------------------------------------------------
// Kernel 1 (UNCHANGED): Em_bf16[m][l][k] = bf16(Cm[m] * sum_n XF[k][n]*Dm[l][n])
// ---------------------------------------------------------------------------
__global__ __launch_bounds__(256) void build_Em(
    const float* __restrict__ Cm,
    const float* __restrict__ XFc,
    const float* __restrict__ XFs,
    const float* __restrict__ Dval,
    const int*   __restrict__ Drow,
    const int*   __restrict__ Dcol,
    int nnz,
    __hip_bfloat16* __restrict__ Em)
{
    __shared__ float Dm[16 * B_];   // [l-l0][n], 4 KB, zero-padded
    const int m  = blockIdx.y;
    const int l0 = blockIdx.x * 16;
    const int t  = threadIdx.x;

    for (int i = t; i < 16 * B_; i += 256) Dm[i] = 0.f;

    int lo, hi;
    {
        int target = m * B_ + l0;
        int a = 0, b = nnz;
        while (a < b) { int mid = (a + b) >> 1; if (Drow[mid] < target) a = mid + 1; else b = mid; }
        lo = a;
        target = m * B_ + l0 + 16;
        b = nnz;
        while (a < b) { int mid = (a + b) >> 1; if (Drow[mid] < target) a = mid + 1; else b = mid; }
        hi = a;
    }
    __syncthreads();
    for (int i = lo + t; i < hi; i += 256) {
        int l = Drow[i] - m * B_ - l0;
        int n = Dcol[i] - m * TWOB_;
        Dm[l * B_ + n] = Dval[i];
    }
    __syncthreads();

    const float* __restrict__ XF = (m & 1) ? XFc : XFs;
    const float cm = Cm[m];
    const int k  = t & 127;
    const int lh = t >> 7;

    const float4* __restrict__ XFrow = reinterpret_cast<const float4*>(XF + k * TWOB_);
    float4 xf[16];
    #pragma unroll
    for (int q = 0; q < 16; ++q) xf[q] = XFrow[q];

    const float4* __restrict__ dmq = reinterpret_cast<const float4*>(Dm) + (lh * 8) * 16;
    float acc[8] = {};
    #pragma unroll
    for (int q = 0; q < 16; ++q) {
        #pragma unroll
        for (int j = 0; j < 8; ++j) {
            float4 dm = dmq[j * 16 + q];
            acc[j] += xf[q].x * dm.x + xf[q].y * dm.y + xf[q].z * dm.z + xf[q].w * dm.w;
        }
    }
    #pragma unroll
    for (int j = 0; j < 8; ++j) {
        int l = l0 + lh * 8 + j;
        Em[(size_t)(m * B_ + l) * TWOB_ + k] = __float2bfloat16(cm * acc[j]);
    }
}

// ---------------------------------------------------------------------------
// Kernel 2: per (m, batch-tile), out[64l x 64b] = E[64l x 128k] @ A[128k x 64b].
// 1024 blocks, mapping: xcd=bid&7, rest=bid>>3, m=xcd+8*(rest&15), tile=rest>>4
//   -> each XCD's L2 sees only 16 distinct Em[m] (256 KB, fetched once).
// Staging via global_load_lds width=16: LDS dest LINEAR (wave base + lane*16),
// swizzle folded into the per-lane GLOBAL source address (u ^= row&15 on 16B
// units). As kept fp32 (32 KB); converted to bf16 at fragment read.
// MFMA operands swapped vs round 4: A-frag=Es rows(l), B-frag=As cols(b), so
// D rows = l -> each lane stores one float4 of 4 consecutive l per b-tile.
// Frag reads: row-stride 256B(Es)/512B(As) + XOR swizzle -> 8 words/bank
// uniform per ds_read_b128 (conflict-free).
// ---------------------------------------------------------------------------
__global__ __launch_bounds__(256) void fdlt_gemm(
    const float* __restrict__ psiHat,
    const __hip_bfloat16* __restrict__ Em,
    float* __restrict__ out)
{
    __shared__ float As[64 * 128];   // fp32 A tile [b][k], 32 KB, unit-swizzled
    __shared__ short Es[64 * 128];   // bf16 E tile [l][k], 16 KB, unit-swizzled

    const int bid  = blockIdx.x;
    const int xcd  = bid & 7;
    const int rest = bid >> 3;
    const int m    = xcd + ((rest & 15) << 3);
    const int tile = rest >> 4;
    if (m >= M_) return;             // 8 guard blocks (m==127), uniform exit
    const int b0 = tile * 64;
    const int t  = threadIdx.x;
    const int wbase = t & 192;       // wave id * 64

    // DMA stage As: 2048 16B-units, 8 per thread. LDS linear, source swizzled.
    #pragma unroll
    for (int j = 0; j < 8; ++j) {
        int L   = t + j * 256;       // LDS unit index
        int row = L >> 5;            // b-row (32 units of 4 floats per row)
        int u   = L & 31;
        int us  = u ^ (row & 15);    // inverse swizzle on source
        const float* src = psiHat + ((size_t)(b0 + row) * M_ + m) * TWOB_ + (us << 2);
        float* dst = As + (size_t)(wbase + j * 256) * 4;   // wave-uniform base
        __builtin_amdgcn_global_load_lds((const uint32_t*)src, (uint32_t*)dst, 16, 0, 0);
    }
    // DMA stage Es: 1024 16B-units, 4 per thread.
    #pragma unroll
    for (int j = 0; j < 4; ++j) {
        int L   = t + j * 256;
        int row = L >> 4;            // l-row (16 units of 8 bf16 per row)
        int u   = L & 15;
        int us  = u ^ (row & 15);
        const __hip_bfloat16* src = Em + (size_t)m * (B_ * TWOB_) + row * TWOB_ + (us << 3);
        short* dst = Es + (size_t)(wbase + j * 256) * 8;
        __builtin_amdgcn_global_load_lds((const uint32_t*)src, (uint32_t*)dst, 16, 0, 0);
    }
    __syncthreads();                 // compiler drains vmcnt before s_barrier

    const int lane = t & 63;
    const int w    = t >> 6;         // wave's l-block: l in [w*16, w*16+16)
    const int lr   = lane & 15;
    const int lg   = lane >> 4;

    f32x4 acc[4];
    #pragma unroll
    for (int nt = 0; nt < 4; ++nt) acc[nt] = (f32x4){0.f, 0.f, 0.f, 0.f};

    const short* __restrict__ ebase = Es + (w * 16 + lr) * TWOB_;

    #pragma unroll
    for (int ks = 0; ks < 4; ++ks) {
        int g = ks * 4 + lg;                       // bf16 16B-unit within l-row
        bf16x8 af = *reinterpret_cast<const bf16x8*>(ebase + ((g ^ lr) << 3));
        #pragma unroll
        for (int nt = 0; nt < 4; ++nt) {           // b-tiles
            int row = nt * 16 + lr;                // b-row in As
            int u0  = ks * 8 + lg * 2;             // fp32 16B-unit pair
            f32x4 p0 = *reinterpret_cast<const f32x4*>(As + row * TWOB_ + (((u0    ) ^ lr) << 2));
            f32x4 p1 = *reinterpret_cast<const f32x4*>(As + row * TWOB_ + (((u0 + 1) ^ lr) << 2));
            bf16x8 bf;
            bf[0] = f2bf(p0[0]); bf[1] = f2bf(p0[1]); bf[2] = f2bf(p0[2]); bf[3] = f2bf(p0[3]);
            bf[4] = f2bf(p1[0]); bf[5] = f2bf(p1[1]); bf[6] = f2bf(p1[2]); bf[7] = f2bf(p1[3]);
            acc[nt] = __builtin_amdgcn_mfma_f32_16x16x32_bf16(af, bf, acc[nt], 0, 0, 0);
        }
    }

    // epilogue: D col = lane&15 = b, row = lg*4+r = l -> float4 of consecutive l
    #pragma unroll
    for (int nt = 0; nt < 4; ++nt) {
        int b = b0 + nt * 16 + lr;
        float4 v;
        v.x = acc[nt][0]; v.y = acc[nt][1]; v.z = acc[nt][2]; v.w = acc[nt][3];
        *reinterpret_cast<float4*>(out + ((size_t)b * M_ + m) * B_ + w * 16 + lg * 4) = v;
    }
}

extern "C" void kernel_launch(void* const* d_in, const int* in_sizes, int n_in,
                              void* d_out, int out_size, void* d_ws, size_t ws_size,
                              hipStream_t stream) {
    const float* psiHat = (const float*)d_in[0];
    const float* Cm     = (const float*)d_in[1];
    const float* XFc    = (const float*)d_in[2];
    const float* XFs    = (const float*)d_in[3];
    const float* Dval   = (const float*)d_in[4];
    const int*   Drow   = (const int*)d_in[5];
    const int*   Dcol   = (const int*)d_in[6];
    const int nnz = in_sizes[4];

    __hip_bfloat16* Em = (__hip_bfloat16*)d_ws;   // 127*64*128*2 = 2,080,768 B

    build_Em<<<dim3(4, M_), dim3(256), 0, stream>>>(Cm, XFc, XFs, Dval, Drow, Dcol, nnz, Em);
    fdlt_gemm<<<dim3(1024), dim3(256), 0, stream>>>(psiHat, Em, (float*)d_out);
}